// Round 13
// baseline (138.772 us; speedup 1.0000x reference)
//
#include <hip/hip_runtime.h>
#include <math.h>

#define RES 192
#define RANK 8
#define NI 128
#define LW 136   // padded LDS row width (halfs)

typedef __attribute__((ext_vector_type(8))) _Float16 h8;
typedef __attribute__((ext_vector_type(2))) _Float16 h2f;
typedef __attribute__((ext_vector_type(4))) float floatx4;

// packed-weight offsets in halfs (each fragment chunk: 64 lanes * 8 fp16)
#define OFF_SW0 0        // 8 ntiles * 1 kstep  * 512 = 4096
#define OFF_SW1 4096     // 8 * 4 * 512 = 16384
#define OFF_SW2 20480    // 1 * 4 * 512 = 2048
#define OFF_CW0 22528    // 4 * 1 * 512 = 2048
#define OFF_CW1 24576    // 4 * 2 * 512 = 4096
#define OFF_CW2 28672    // 1 * 2 * 512 = 1024
#define PACK_TOTAL 29696

#define TRI_CELLS (RES*RES)          // 36864 cells per plane
#define TRI_TOTAL (3*TRI_CELLS*24)   // 2654208
#define FG_TOTAL  (32*32*32*32)      // 1048576
#define PREP_TOTAL (PACK_TOTAL + TRI_TOTAL + FG_TOTAL)   // 3732480 = 14580*256

__device__ __forceinline__ void prep_idx(float c, int size, int& i0, float& f){
    float idx = (c + 1.0f)*0.5f*(float)(size-1);
    idx = fminf(fmaxf(idx, 0.0f), (float)(size-1));
    int ii = (int)idx;               // idx >= 0, trunc == floor
    if (ii > size-2) ii = size-2;
    i0 = ii;
    f = idx - (float)ii;
}

__device__ __forceinline__ float wred64(float v){
    #pragma unroll
    for (int o=32;o>0;o>>=1) v += __shfl_down(v, o, 64);
    return v;
}

__device__ __forceinline__ float hsum8(h8 a){
    h2f x = __builtin_shufflevector(a,a,0,1) + __builtin_shufflevector(a,a,2,3);
    h2f y = __builtin_shufflevector(a,a,4,5) + __builtin_shufflevector(a,a,6,7);
    h2f z = x + y;
    return (float)z[0] + (float)z[1];
}

// ---- fused prep: weight packing + fp16 table conversion ----
__global__ void __launch_bounds__(256) prep_all(
    const float* __restrict__ sW0, const float* __restrict__ sW1,
    const float* __restrict__ sW2, const float* __restrict__ cW0,
    const float* __restrict__ cW1, const float* __restrict__ cW2,
    const float* __restrict__ Gxy, const float* __restrict__ Gxz,
    const float* __restrict__ Gyz, const float* __restrict__ F_grid,
    _Float16* __restrict__ Wp, _Float16* __restrict__ Gp, _Float16* __restrict__ Fg)
{
    int e = blockIdx.x*256 + threadIdx.x;
    if (e < PACK_TOTAL){
        const float* src; int K, N, ksteps, base;
        if      (e < OFF_SW1){ src=sW0; K=32;  N=128; ksteps=1; base=OFF_SW0; }
        else if (e < OFF_SW2){ src=sW1; K=128; N=128; ksteps=4; base=OFF_SW1; }
        else if (e < OFF_CW0){ src=sW2; K=128; N=16;  ksteps=4; base=OFF_SW2; }
        else if (e < OFF_CW1){ src=cW0; K=31;  N=64;  ksteps=1; base=OFF_CW0; }
        else if (e < OFF_CW2){ src=cW1; K=64;  N=64;  ksteps=2; base=OFF_CW1; }
        else                 { src=cW2; K=64;  N=3;   ksteps=2; base=OFF_CW2; }
        int i = e - base;
        int j = i & 7, lane = (i>>3)&63, t = i>>9;
        int ks = t % ksteps, nt = t / ksteps;
        int k = ks*32 + (lane>>4)*8 + j;
        int n = nt*16 + (lane&15);
        float v = (k < K && n < N) ? src[k*N + n] : 0.0f;
        Wp[e] = (_Float16)v;
        return;
    }
    int e2 = e - PACK_TOTAL;
    if (e2 < TRI_TOTAL){
        int p    = e2 / (TRI_CELLS*24);
        int rem  = e2 - p*(TRI_CELLS*24);
        int cell = rem / 24;
        int c    = rem - cell*24;
        const float* src = (p==0) ? Gxy : (p==1) ? Gxz : Gyz;
        Gp[((size_t)(p*TRI_CELLS + cell))*32 + c] = (_Float16)src[(size_t)cell*24 + c];
        return;
    }
    int e3 = e2 - TRI_TOTAL;
    Fg[e3] = (_Float16)F_grid[e3];
}

// --------- fused kernel: gather + MFMA MLPs + compositing (block = ray) ---------
// 512 threads = 8 waves; wave wv owns samples/rows [16wv,16wv+16) end-to-end:
// gather (4 lanes/sample: corner (zc,yc) + F-grid ch-quarter) -> own buf rows ->
// 6 MFMA layers (one 16x16 M-tile/wave), no inter-phase barriers; then composite.
// LDS unchanged -> 4 blocks/CU -> 32 waves/CU (100% slot capacity).
__launch_bounds__(512, 8)   // 8 waves/EU => VGPR cap 64 (round-12 used exactly 64)
__global__ void nerf_fused(
    const float* __restrict__ rays_o, const float* __restrict__ rays_d,
    const _Float16* __restrict__ Gp, const _Float16* __restrict__ Fg,
    const _Float16* __restrict__ Wp, float* __restrict__ out)
{
    __shared__ _Float16 buf[128*LW];     // activations; rows are WAVE-PRIVATE
    __shared__ float sigmaArr[128];
    __shared__ float rgbArr[128*3];
    __shared__ float wtot[2];
    __shared__ float partial[8];

    const int tid  = threadIdx.x;
    const int lane = tid & 63;
    const int wv   = tid >> 6;           // wave 0..7
    const int ray  = blockIdx.x;

    const int rowbase = wv*16;
    const int col  = lane & 15;
    const int quad = lane >> 4;
    const int ar   = rowbase + col;      // A row (single M tile)

    const float ox = rays_o[ray*3+0], oy = rays_o[ray*3+1], oz = rays_o[ray*3+2];
    const float dx = rays_d[ray*3+0], dy = rays_d[ray*3+1], dz = rays_d[ray*3+2];

    float sdx = (fabsf(dx) < 1e-9f) ? 1e-9f : dx;
    float sdy = (fabsf(dy) < 1e-9f) ? 1e-9f : dy;
    float sdz = (fabsf(dz) < 1e-9f) ? 1e-9f : dz;
    float t1x = (-1.3f - ox)/sdx, t2x = (1.3f - ox)/sdx;
    float t1y = (-1.3f - oy)/sdy, t2y = (1.3f - oy)/sdy;
    float t1z = (-1.3f - oz)/sdz, t2z = (1.3f - oz)/sdz;
    float tmin = fmaxf(fminf(t1x,t2x), fmaxf(fminf(t1y,t2y), fminf(t1z,t2z)));
    float tmax = fminf(fmaxf(t1x,t2x), fminf(fmaxf(t1y,t2y), fmaxf(t1z,t2z)));
    float nearv = fmaxf(tmin, 0.0f);

    // per-lane sample assignment for gather (4 lanes/sample)
    const int s   = rowbase + (lane >> 2);
    const int sub = lane & 3;            // (zc,yc) corner + F-grid ch-quarter
    const int zc  = sub & 1;
    const int yc  = sub >> 1;

    float ts0 = nearv + (float)s     * 0.0352f;
    float ts1 = nearv + (float)(s+1) * 0.0352f;
    float tmid = 0.5f*(ts0+ts1);
    float px = ox + tmid*dx, py = oy + tmid*dy, pz = oz + tmid*dz;
    bool mask = (fabsf(px)<=1.3f) && (fabsf(py)<=1.3f) && (fabsf(pz)<=1.3f)
              && (tmid<=tmax) && (tmax>tmin);

    // wave-skip: all 16 samples masked -> outputs never read
    if (__ballot(mask) != 0ULL){
        // ---- gather ----
        {
            h8 FV = {0,0,0,0,0,0,0,0};
            if (mask){
                float p0 = (px/1.3f + 1.0f)*192.0f/2.0f*2.0f/192.0f - 1.0f;
                float p1 = (py/1.3f + 1.0f)*192.0f/2.0f*2.0f/192.0f - 1.0f;
                float p2 = (pz/1.3f + 1.0f)*192.0f/2.0f*2.0f/192.0f - 1.0f;

                int x0, y0, z0; float fx, fy, fz;
                prep_idx(p0, RES, x0, fx);
                prep_idx(p1, RES, y0, fy);
                prep_idx(p2, RES, z0, fz);

                const int zi = z0 + zc;
                const int yi = y0 + yc;
                const float wzy = (zc ? fz : 1.0f-fz) * (yc ? fy : 1.0f-fy);

                h8 XYc[3], XZ0[3], XZ1[3], YZ0[3], YZ1[3];
                {
                    const h8* pxy = (const h8*)(Gp + ((size_t)(zi*RES + yi))*32);
                    const h8* px0 = (const h8*)(Gp + ((size_t)(TRI_CELLS + zi*RES + x0  ))*32);
                    const h8* px1 = (const h8*)(Gp + ((size_t)(TRI_CELLS + zi*RES + x0+1))*32);
                    const h8* py0 = (const h8*)(Gp + ((size_t)(2*TRI_CELLS + yi*RES + x0  ))*32);
                    const h8* py1 = (const h8*)(Gp + ((size_t)(2*TRI_CELLS + yi*RES + x0+1))*32);
                    #pragma unroll
                    for (int q=0;q<3;q++){
                        XYc[q]=pxy[q];
                        XZ0[q]=px0[q]; XZ1[q]=px1[q];
                        YZ0[q]=py0[q]; YZ1[q]=py1[q];
                    }
                }

                h8 ACC0, ACC1, ACC2;
                {
                    const _Float16 w0 = (_Float16)(wzy*(1.0f-fx));
                    const _Float16 w1 = (_Float16)(wzy*fx);
                    const h8 w80 = {w0,w0,w0,w0,w0,w0,w0,w0};
                    const h8 w81 = {w1,w1,w1,w1,w1,w1,w1,w1};
                    ACC0 = (XYc[0]*XZ0[0])*YZ0[0]*w80;
                    ACC1 = (XYc[1]*XZ0[1])*YZ0[1]*w80;
                    ACC2 = (XYc[2]*XZ0[2])*YZ0[2]*w80;
                    ACC0 = __builtin_elementwise_fma((XYc[0]*XZ1[0])*YZ1[0], w81, ACC0);
                    ACC1 = __builtin_elementwise_fma((XYc[1]*XZ1[1])*YZ1[1], w81, ACC1);
                    ACC2 = __builtin_elementwise_fma((XYc[2]*XZ1[2])*YZ1[2], w81, ACC2);
                }
                float gv0 = hsum8(ACC0);
                float gv1 = hsum8(ACC1);
                float gv2 = hsum8(ACC2);
                // reduce over the 4 corner-lanes (quad shares identical mask)
                gv0 += __shfl_xor(gv0, 1, 64); gv0 += __shfl_xor(gv0, 2, 64);
                gv1 += __shfl_xor(gv1, 1, 64); gv1 += __shfl_xor(gv1, 2, 64);
                gv2 += __shfl_xor(gv2, 1, 64); gv2 += __shfl_xor(gv2, 2, 64);

                // F-grid: this lane computes channels [8*sub, 8*sub+8) of all 8 corners
                int a0,b0,c0; float fa,fb,fc;
                prep_idx(gv2, 32, a0, fa);
                prep_idx(gv1, 32, b0, fb);
                prep_idx(gv0, 32, c0, fc);
                #pragma unroll
                for (int zc2=0; zc2<2; zc2++){
                    const int zi2 = a0+zc2; const float wz2 = zc2 ? fa : 1.f-fa;
                    #pragma unroll
                    for (int yc2=0; yc2<2; yc2++){
                        const int yi2 = b0+yc2; const float wy2 = yc2 ? fb : 1.f-fb;
                        #pragma unroll
                        for (int xc2=0; xc2<2; xc2++){
                            const int xi2 = c0+xc2; const float wx2 = xc2 ? fc : 1.f-fc;
                            const _Float16 wh = (_Float16)(wz2*wy2*wx2);
                            const h8 w8 = {wh,wh,wh,wh,wh,wh,wh,wh};
                            const h8* pf = (const h8*)(Fg + ((size_t)((zi2*32+yi2)*32+xi2))*32 + sub*8);
                            FV = __builtin_elementwise_fma(pf[0], w8, FV);
                        }
                    }
                }
            }
            *(h8*)&buf[s*LW + sub*8] = FV;   // intra-wave LDS ordering via lgkmcnt
        }

        // L1: 32 -> 128, relu (in-place safe: A register-resident first)
        {
            h8 a = *(const h8*)&buf[ar*LW + quad*8];
            const h8* W = (const h8*)(Wp + OFF_SW0);
            #pragma unroll
            for (int nt=0; nt<8; nt++){
                h8 b = W[nt*64 + lane];
                floatx4 cv = {0.f,0.f,0.f,0.f};
                cv = __builtin_amdgcn_mfma_f32_16x16x32_f16(a, b, cv, 0,0,0);
                #pragma unroll
                for (int r=0;r<4;r++){
                    int row = rowbase + quad*4 + r;
                    buf[row*LW + nt*16 + col] = (_Float16)fmaxf(cv[r],0.f);
                }
            }
        }

        // L2: 128 -> 128, relu
        {
            h8 A[4];
            #pragma unroll
            for (int ks=0;ks<4;ks++) A[ks] = *(const h8*)&buf[ar*LW + ks*32 + quad*8];
            const h8* W = (const h8*)(Wp + OFF_SW1);
            #pragma unroll
            for (int nt=0; nt<8; nt++){
                floatx4 cv = {0.f,0.f,0.f,0.f};
                #pragma unroll
                for (int ks=0;ks<4;ks++){
                    h8 b = W[(nt*4+ks)*64 + lane];
                    cv = __builtin_amdgcn_mfma_f32_16x16x32_f16(A[ks], b, cv, 0,0,0);
                }
                #pragma unroll
                for (int r=0;r<4;r++){
                    int row = rowbase + quad*4 + r;
                    buf[row*LW + nt*16 + col] = (_Float16)fmaxf(cv[r],0.f);
                }
            }
        }

        // L3: 128 -> 16 (no relu); col0 -> sigmaArr, cols 1..15 -> buf 16..30
        {
            h8 A[4];
            #pragma unroll
            for (int ks=0;ks<4;ks++) A[ks] = *(const h8*)&buf[ar*LW + ks*32 + quad*8];
            const h8* W = (const h8*)(Wp + OFF_SW2);
            floatx4 cv = {0.f,0.f,0.f,0.f};
            #pragma unroll
            for (int ks=0;ks<4;ks++){
                h8 b = W[ks*64 + lane];
                cv = __builtin_amdgcn_mfma_f32_16x16x32_f16(A[ks], b, cv, 0,0,0);
            }
            #pragma unroll
            for (int r=0;r<4;r++){
                int row = rowbase + quad*4 + r;
                if (col == 0) sigmaArr[row] = cv[r];
                else          buf[row*LW + 15 + col] = (_Float16)cv[r];
            }
            // SH basis (ray-uniform) -> cols 0..15 of this wave's 16 rows
            const float dn = sqrtf(dx*dx+dy*dy+dz*dz);
            const float X = dx/dn, Y = dy/dn, Z = dz/dn;
            const float X2=X*X, Y2=Y*Y, Z2=Z*Z;
            float sh[16];
            sh[0]= 0.28209479177387814f;
            sh[1]=-0.48860251190291987f*Y;
            sh[2]= 0.48860251190291987f*Z;
            sh[3]=-0.48860251190291987f*X;
            sh[4]= 1.0925484305920792f*X*Y;
            sh[5]=-1.0925484305920792f*Y*Z;
            sh[6]= 0.94617469575756f*Z2 - 0.31539156525252f;
            sh[7]=-1.0925484305920792f*X*Z;
            sh[8]= 0.5462742152960396f*(X2-Y2);
            sh[9]= 0.5900435899266435f*Y*(-3.0f*X2+Y2);
            sh[10]=2.890611442640554f*X*Y*Z;
            sh[11]=0.4570457994644657f*Y*(1.0f-5.0f*Z2);
            sh[12]=0.3731763325901154f*Z*(5.0f*Z2-3.0f);
            sh[13]=0.4570457994644657f*X*(1.0f-5.0f*Z2);
            sh[14]=1.445305721320277f*Z*(X2-Y2);
            sh[15]=0.5900435899266435f*X*(-X2+3.0f*Y2);
            if (lane < 16){
                int row = rowbase + lane;
                #pragma unroll
                for (int k=0;k<16;k++) buf[row*LW + k] = (_Float16)sh[k];
            }
        }

        // CL1: 31(pad32) -> 64, relu
        {
            h8 a = *(const h8*)&buf[ar*LW + quad*8];
            const h8* W = (const h8*)(Wp + OFF_CW0);
            #pragma unroll
            for (int nt=0; nt<4; nt++){
                h8 b = W[nt*64 + lane];
                floatx4 cv = {0.f,0.f,0.f,0.f};
                cv = __builtin_amdgcn_mfma_f32_16x16x32_f16(a, b, cv, 0,0,0);
                #pragma unroll
                for (int r=0;r<4;r++){
                    int row = rowbase + quad*4 + r;
                    buf[row*LW + nt*16 + col] = (_Float16)fmaxf(cv[r],0.f);
                }
            }
        }

        // CL2: 64 -> 64, relu
        {
            h8 A[2];
            #pragma unroll
            for (int ks=0;ks<2;ks++) A[ks] = *(const h8*)&buf[ar*LW + ks*32 + quad*8];
            const h8* W = (const h8*)(Wp + OFF_CW1);
            #pragma unroll
            for (int nt=0; nt<4; nt++){
                floatx4 cv = {0.f,0.f,0.f,0.f};
                #pragma unroll
                for (int ks=0;ks<2;ks++){
                    h8 b = W[(nt*2+ks)*64 + lane];
                    cv = __builtin_amdgcn_mfma_f32_16x16x32_f16(A[ks], b, cv, 0,0,0);
                }
                #pragma unroll
                for (int r=0;r<4;r++){
                    int row = rowbase + quad*4 + r;
                    buf[row*LW + nt*16 + col] = (_Float16)fmaxf(cv[r],0.f);
                }
            }
        }

        // CL3: 64 -> 3, no relu -> rgbArr
        {
            h8 A[2];
            #pragma unroll
            for (int ks=0;ks<2;ks++) A[ks] = *(const h8*)&buf[ar*LW + ks*32 + quad*8];
            const h8* W = (const h8*)(Wp + OFF_CW2);
            floatx4 cv = {0.f,0.f,0.f,0.f};
            #pragma unroll
            for (int ks=0;ks<2;ks++){
                h8 b = W[ks*64 + lane];
                cv = __builtin_amdgcn_mfma_f32_16x16x32_f16(A[ks], b, cv, 0,0,0);
            }
            if (col < 3){
                #pragma unroll
                for (int r=0;r<4;r++){
                    int row = rowbase + quad*4 + r;
                    rgbArr[row*3 + col] = cv[r];
                }
            }
        }
    }

    __syncthreads();   // cross-wave handoff: sigmaArr/rgbArr -> waves 0,1

    // ---------------- compositing (threads 0..127, sample = tid) ----------------
    {
        float alpha = 0.f, rr = 0.f, rg = 0.f, rb = 0.f;
        if (tid < 128){
            float cts0 = nearv + (float)tid     * 0.0352f;
            float cts1 = nearv + (float)(tid+1) * 0.0352f;
            float ctm  = 0.5f*(cts0+cts1);
            float dist = cts1 - cts0;
            float cpx = ox + ctm*dx, cpy = oy + ctm*dy, cpz = oz + ctm*dz;
            bool cmask = (fabsf(cpx)<=1.3f) && (fabsf(cpy)<=1.3f) && (fabsf(cpz)<=1.3f)
                       && (ctm<=tmax) && (tmax>tmin);
            float sg = cmask ? fmaxf(sigmaArr[tid], 0.f) : 0.f;
            alpha = 1.0f - expf(-sg*dist);
            if (cmask){
                rr = 1.0f/(1.0f+expf(-rgbArr[tid*3+0]));
                rg = 1.0f/(1.0f+expf(-rgbArr[tid*3+1]));
                rb = 1.0f/(1.0f+expf(-rgbArr[tid*3+2]));
            }
        }
        float p = 1.0f - alpha + 1e-10f;
        #pragma unroll
        for (int off=1; off<64; off<<=1){
            float u = __shfl_up(p, off, 64);
            if (lane >= off) p *= u;
        }
        if (tid < 128 && lane == 63) wtot[wv] = p;
        float excl = __shfl_up(p, 1, 64);
        if (lane == 0) excl = 1.0f;
        __syncthreads();
        if (tid < 128){
            float T = excl;
            if (wv == 1) T *= wtot[0];
            float w = alpha * T;
            float v0 = wred64(w*rr);
            float v1 = wred64(w*rg);
            float v2 = wred64(w*rb);
            float v3 = wred64(w);
            if (lane == 0){
                partial[wv*4+0]=v0; partial[wv*4+1]=v1; partial[wv*4+2]=v2; partial[wv*4+3]=v3;
            }
        }
        __syncthreads();
        if (tid == 0){
            float acc = partial[3] + partial[7];
            float bg  = 1.0f - acc;
            out[ray*3+0] = partial[0] + partial[4] + bg;
            out[ray*3+1] = partial[1] + partial[5] + bg;
            out[ray*3+2] = partial[2] + partial[6] + bg;
        }
    }
}

extern "C" void kernel_launch(void* const* d_in, const int* in_sizes, int n_in,
                              void* d_out, int out_size, void* d_ws, size_t ws_size,
                              hipStream_t stream){
    const float* rays_o = (const float*)d_in[0];
    const float* rays_d = (const float*)d_in[1];
    const float* Gxy    = (const float*)d_in[2];
    const float* Gxz    = (const float*)d_in[3];
    const float* Gyz    = (const float*)d_in[4];
    const float* F_grid = (const float*)d_in[5];
    const float* sW0    = (const float*)d_in[6];
    const float* sW1    = (const float*)d_in[7];
    const float* sW2    = (const float*)d_in[8];
    const float* cW0    = (const float*)d_in[9];
    const float* cW1    = (const float*)d_in[10];
    const float* cW2    = (const float*)d_in[11];

    _Float16* Wp = (_Float16*)d_ws;                     // packed weights (59.4 KB)
    _Float16* Gp = Wp + PACK_TOTAL;                     // padded fp16 triplanes, 7.08 MB
    _Float16* Fg = Gp + (size_t)3*TRI_CELLS*32;         // fp16 F_grid, 2.1 MB

    prep_all<<<PREP_TOTAL/256, 256, 0, stream>>>(sW0,sW1,sW2,cW0,cW1,cW2,
                                                 Gxy,Gxz,Gyz,F_grid, Wp,Gp,Fg);
    nerf_fused<<<2048, 512, 0, stream>>>(rays_o, rays_d, Gp, Fg, Wp, (float*)d_out);
}

// Round 15
// 133.331 us; speedup vs baseline: 1.0408x; 1.0408x over previous
//
#include <hip/hip_runtime.h>
#include <math.h>

#define RES 192
#define RANK 8
#define NI 128
#define LW 136   // padded LDS row width (halfs)

typedef __attribute__((ext_vector_type(8))) _Float16 h8;
typedef __attribute__((ext_vector_type(4))) _Float16 h4;
typedef __attribute__((ext_vector_type(2))) _Float16 h2f;
typedef __attribute__((ext_vector_type(2))) __fp16 fp16x2;
typedef __attribute__((ext_vector_type(4))) float floatx4;

// packed-weight offsets in halfs (each fragment chunk: 64 lanes * 8 fp16)
#define OFF_SW0 0        // 8 ntiles * 1 kstep  * 512 = 4096
#define OFF_SW1 4096     // 8 * 4 * 512 = 16384
#define OFF_SW2 20480    // 1 * 4 * 512 = 2048
#define OFF_CW0 22528    // 4 * 1 * 512 = 2048
#define OFF_CW1 24576    // 4 * 2 * 512 = 4096
#define OFF_CW2 28672    // 1 * 2 * 512 = 1024
#define PACK_TOTAL 29696

#define TRI_CELLS (RES*RES)          // 36864 cells per plane
#define TRI_TOTAL (3*TRI_CELLS*24)   // 2654208
#define FG_TOTAL  (32*32*32*32)      // 1048576
#define PREP_TOTAL (PACK_TOTAL + TRI_TOTAL + FG_TOTAL)   // 3732480 = 14580*256

__device__ __forceinline__ void prep_idx(float c, int size, int& i0, float& f){
    float idx = (c + 1.0f)*0.5f*(float)(size-1);
    idx = fminf(fmaxf(idx, 0.0f), (float)(size-1));
    int ii = (int)idx;               // idx >= 0, trunc == floor
    if (ii > size-2) ii = size-2;
    i0 = ii;
    f = idx - (float)ii;
}

__device__ __forceinline__ float wred64(float v){
    #pragma unroll
    for (int o=32;o>0;o>>=1) v += __shfl_down(v, o, 64);
    return v;
}

// pair exchange: xor-1 lane shuffle of an h8 (4 dword moves)
__device__ __forceinline__ h8 shx1(h8 v){
    union { h8 h; int i[4]; } u; u.h = v;
    #pragma unroll
    for (int k=0;k<4;k++) u.i[k] = __shfl_xor(u.i[k], 1, 64);
    return u.h;
}

// relu + pack 4 f32 -> 4 f16 (two v_cvt_pkrtz); union reinterprets __fp16->_Float16
__device__ __forceinline__ h4 pack_relu(floatx4 cv){
    union { fp16x2 p[2]; h4 h; } u;
    u.p[0] = __builtin_amdgcn_cvt_pkrtz(fmaxf(cv[0],0.f), fmaxf(cv[1],0.f));
    u.p[1] = __builtin_amdgcn_cvt_pkrtz(fmaxf(cv[2],0.f), fmaxf(cv[3],0.f));
    return u.h;
}

// ---- fused prep: weight packing + fp16 table conversion ----
__global__ void __launch_bounds__(256) prep_all(
    const float* __restrict__ sW0, const float* __restrict__ sW1,
    const float* __restrict__ sW2, const float* __restrict__ cW0,
    const float* __restrict__ cW1, const float* __restrict__ cW2,
    const float* __restrict__ Gxy, const float* __restrict__ Gxz,
    const float* __restrict__ Gyz, const float* __restrict__ F_grid,
    _Float16* __restrict__ Wp, _Float16* __restrict__ Gp, _Float16* __restrict__ Fg)
{
    int e = blockIdx.x*256 + threadIdx.x;
    if (e < PACK_TOTAL){
        const float* src; int K, N, ksteps, base;
        if      (e < OFF_SW1){ src=sW0; K=32;  N=128; ksteps=1; base=OFF_SW0; }
        else if (e < OFF_SW2){ src=sW1; K=128; N=128; ksteps=4; base=OFF_SW1; }
        else if (e < OFF_CW0){ src=sW2; K=128; N=16;  ksteps=4; base=OFF_SW2; }
        else if (e < OFF_CW1){ src=cW0; K=31;  N=64;  ksteps=1; base=OFF_CW0; }
        else if (e < OFF_CW2){ src=cW1; K=64;  N=64;  ksteps=2; base=OFF_CW1; }
        else                 { src=cW2; K=64;  N=3;   ksteps=2; base=OFF_CW2; }
        int i = e - base;
        int j = i & 7, lane = (i>>3)&63, t = i>>9;
        int ks = t % ksteps, nt = t / ksteps;
        int k = ks*32 + (lane>>4)*8 + j;
        int n = nt*16 + (lane&15);
        float v = (k < K && n < N) ? src[k*N + n] : 0.0f;
        Wp[e] = (_Float16)v;
        return;
    }
    int e2 = e - PACK_TOTAL;
    if (e2 < TRI_TOTAL){
        int p    = e2 / (TRI_CELLS*24);
        int rem  = e2 - p*(TRI_CELLS*24);
        int cell = rem / 24;
        int c    = rem - cell*24;
        const float* src = (p==0) ? Gxy : (p==1) ? Gxz : Gyz;
        Gp[((size_t)(p*TRI_CELLS + cell))*32 + c] = (_Float16)src[(size_t)cell*24 + c];
        return;
    }
    int e3 = e2 - TRI_TOTAL;
    Fg[e3] = (_Float16)F_grid[e3];
}

// --------- fused kernel: gather + MFMA MLPs + compositing (block = ray) ---------
// Round-12 structure (4 waves, wave owns rows [32wv,32wv+32), 2 lanes/sample
// gather with YZ dedup). MFMA operands SWAPPED (A=weights, B=activations) so
// C holds sample=col, 4 consecutive out-channels=quad*4+r -> packed b64 stores.
__launch_bounds__(256, 4)
__global__ void nerf_fused(
    const float* __restrict__ rays_o, const float* __restrict__ rays_d,
    const _Float16* __restrict__ Gp, const _Float16* __restrict__ Fg,
    const _Float16* __restrict__ Wp, float* __restrict__ out)
{
    __shared__ _Float16 buf[128*LW];     // activations [sample][ch]; rows WAVE-PRIVATE
    __shared__ float sigmaArr[128];
    __shared__ float rgbArr[128*3];
    __shared__ float wtot[2];
    __shared__ float partial[8];

    const int tid  = threadIdx.x;
    const int lane = tid & 63;
    const int wv   = tid >> 6;           // wave 0..3
    const int ray  = blockIdx.x;

    const int rowbase = wv*32;
    const int col  = lane & 15;
    const int quad = lane >> 4;
    const int sr0  = rowbase + col;      // sample row, tile 0
    const int sr1  = sr0 + 16;           // sample row, tile 1

    const float ox = rays_o[ray*3+0], oy = rays_o[ray*3+1], oz = rays_o[ray*3+2];
    const float dx = rays_d[ray*3+0], dy = rays_d[ray*3+1], dz = rays_d[ray*3+2];

    float sdx = (fabsf(dx) < 1e-9f) ? 1e-9f : dx;
    float sdy = (fabsf(dy) < 1e-9f) ? 1e-9f : dy;
    float sdz = (fabsf(dz) < 1e-9f) ? 1e-9f : dz;
    float t1x = (-1.3f - ox)/sdx, t2x = (1.3f - ox)/sdx;
    float t1y = (-1.3f - oy)/sdy, t2y = (1.3f - oy)/sdy;
    float t1z = (-1.3f - oz)/sdz, t2z = (1.3f - oz)/sdz;
    float tmin = fmaxf(fminf(t1x,t2x), fmaxf(fminf(t1y,t2y), fminf(t1z,t2z)));
    float tmax = fminf(fmaxf(t1x,t2x), fminf(fmaxf(t1y,t2y), fmaxf(t1z,t2z)));
    float nearv = fmaxf(tmin, 0.0f);

    // wave-skip: if all 32 samples of this wave are masked, outputs never read
    bool skipAll;
    {
        int sid = rowbase + (lane & 31);
        float w_ts0 = nearv + (float)sid     * 0.0352f;
        float w_ts1 = nearv + (float)(sid+1) * 0.0352f;
        float w_tm  = 0.5f*(w_ts0+w_ts1);
        float wpx = ox + w_tm*dx, wpy = oy + w_tm*dy, wpz = oz + w_tm*dz;
        bool m = (fabsf(wpx)<=1.3f) && (fabsf(wpy)<=1.3f) && (fabsf(wpz)<=1.3f)
               && (w_tm<=tmax) && (tmax>tmin);
        skipAll = (__ballot(m) == 0ULL);
    }

    if (!skipAll){
        // ---- gather: 2 lanes per sample (zc half / F-grid ch half) ----
        {
            const int s = rowbase + (lane >> 1);
            const int h = lane & 1;

            float ts0 = nearv + (float)s     * 0.0352f;
            float ts1 = nearv + (float)(s+1) * 0.0352f;
            float tmid = 0.5f*(ts0+ts1);
            float px = ox + tmid*dx, py = oy + tmid*dy, pz = oz + tmid*dz;
            bool mask = (fabsf(px)<=1.3f) && (fabsf(py)<=1.3f) && (fabsf(pz)<=1.3f)
                      && (tmid<=tmax) && (tmax>tmin);

            h8 FVa = {0,0,0,0,0,0,0,0};
            h8 FVb = {0,0,0,0,0,0,0,0};

            if (mask){
                float p0 = (px/1.3f + 1.0f)*192.0f/2.0f*2.0f/192.0f - 1.0f;
                float p1 = (py/1.3f + 1.0f)*192.0f/2.0f*2.0f/192.0f - 1.0f;
                float p2 = (pz/1.3f + 1.0f)*192.0f/2.0f*2.0f/192.0f - 1.0f;

                int x0, y0, z0; float fx, fy, fz;
                prep_idx(p0, RES, x0, fx);
                prep_idx(p1, RES, y0, fy);
                prep_idx(p2, RES, z0, fz);

                const int zi  = z0 + h;
                const float wzc = h ? fz : (1.0f - fz);
                const int yiA = y0 + h;        // yc = h    (yo=0)
                const int yiB = y0 + 1 - h;    // yc = 1-h  (yo=1)

                h8 XYA[3], XYB[3], XZ0[3], XZ1[3], YZo0[3], YZo1[3];
                {
                    const h8* pxyA = (const h8*)(Gp + ((size_t)(zi*RES + yiA))*32);
                    const h8* pxyB = (const h8*)(Gp + ((size_t)(zi*RES + yiB))*32);
                    const h8* px0  = (const h8*)(Gp + ((size_t)(TRI_CELLS + zi*RES + x0  ))*32);
                    const h8* px1  = (const h8*)(Gp + ((size_t)(TRI_CELLS + zi*RES + x0+1))*32);
                    const h8* py0  = (const h8*)(Gp + ((size_t)(2*TRI_CELLS + yiA*RES + x0  ))*32);
                    const h8* py1  = (const h8*)(Gp + ((size_t)(2*TRI_CELLS + yiA*RES + x0+1))*32);
                    #pragma unroll
                    for (int q=0;q<3;q++){
                        XYA[q]=pxyA[q]; XYB[q]=pxyB[q];
                        XZ0[q]=px0[q];  XZ1[q]=px1[q];
                        YZo0[q]=py0[q]; YZo1[q]=py1[q];
                    }
                }
                // partner's YZ row (yc = 1-h); pair lanes have identical mask
                h8 YZp0[3], YZp1[3];
                #pragma unroll
                for (int q=0;q<3;q++){ YZp0[q]=shx1(YZo0[q]); YZp1[q]=shx1(YZo1[q]); }

                const float wyA = h ? fy : (1.0f - fy);
                const float wyB = h ? (1.0f - fy) : fy;

                h8 ACC0 = {0,0,0,0,0,0,0,0};
                h8 ACC1 = {0,0,0,0,0,0,0,0};
                h8 ACC2 = {0,0,0,0,0,0,0,0};
                #pragma unroll
                for (int yo=0; yo<2; yo++){
                    const float wy = yo ? wyB : wyA;
                    #pragma unroll
                    for (int xc=0; xc<2; xc++){
                        const float wx = xc ? fx : (1.0f - fx);
                        const _Float16 wh = (_Float16)(wzc*wy*wx);
                        const h8 w8 = {wh,wh,wh,wh,wh,wh,wh,wh};
                        h8 Q0, Q1, Q2;
                        if (yo==0){
                            const h8* YZv = xc ? YZo1 : YZo0;
                            Q0 = (XYA[0]*(xc?XZ1[0]:XZ0[0]))*YZv[0];
                            Q1 = (XYA[1]*(xc?XZ1[1]:XZ0[1]))*YZv[1];
                            Q2 = (XYA[2]*(xc?XZ1[2]:XZ0[2]))*YZv[2];
                        } else {
                            const h8* YZv = xc ? YZp1 : YZp0;
                            Q0 = (XYB[0]*(xc?XZ1[0]:XZ0[0]))*YZv[0];
                            Q1 = (XYB[1]*(xc?XZ1[1]:XZ0[1]))*YZv[1];
                            Q2 = (XYB[2]*(xc?XZ1[2]:XZ0[2]))*YZv[2];
                        }
                        ACC0 = __builtin_elementwise_fma(Q0, w8, ACC0);
                        ACC1 = __builtin_elementwise_fma(Q1, w8, ACC1);
                        ACC2 = __builtin_elementwise_fma(Q2, w8, ACC2);
                    }
                }
                // horizontal sums 8 -> 1
                h2f a0h = __builtin_shufflevector(ACC0,ACC0,0,1) + __builtin_shufflevector(ACC0,ACC0,2,3);
                h2f b0h = __builtin_shufflevector(ACC0,ACC0,4,5) + __builtin_shufflevector(ACC0,ACC0,6,7);
                h2f c0h = a0h + b0h;
                float gv0 = (float)c0h[0] + (float)c0h[1];
                h2f a1h = __builtin_shufflevector(ACC1,ACC1,0,1) + __builtin_shufflevector(ACC1,ACC1,2,3);
                h2f b1h = __builtin_shufflevector(ACC1,ACC1,4,5) + __builtin_shufflevector(ACC1,ACC1,6,7);
                h2f c1h = a1h + b1h;
                float gv1 = (float)c1h[0] + (float)c1h[1];
                h2f a2h = __builtin_shufflevector(ACC2,ACC2,0,1) + __builtin_shufflevector(ACC2,ACC2,2,3);
                h2f b2h = __builtin_shufflevector(ACC2,ACC2,4,5) + __builtin_shufflevector(ACC2,ACC2,6,7);
                h2f c2h = a2h + b2h;
                float gv2 = (float)c2h[0] + (float)c2h[1];

                // combine the two zc halves
                gv0 += __shfl_xor(gv0, 1, 64);
                gv1 += __shfl_xor(gv1, 1, 64);
                gv2 += __shfl_xor(gv2, 1, 64);

                // F-grid: channels [16h,16h+16) of all 8 corners
                int a0,b0,c0; float fa,fb,fc;
                prep_idx(gv2, 32, a0, fa);
                prep_idx(gv1, 32, b0, fb);
                prep_idx(gv0, 32, c0, fc);
                #pragma unroll
                for (int zc=0; zc<2; zc++){
                    const int zi2 = a0+zc; const float wz2 = zc ? fa : 1.f-fa;
                    #pragma unroll
                    for (int yc=0; yc<2; yc++){
                        const int yi2 = b0+yc; const float wy2 = yc ? fb : 1.f-fb;
                        #pragma unroll
                        for (int xc=0; xc<2; xc++){
                            const int xi2 = c0+xc; const float wx2 = xc ? fc : 1.f-fc;
                            const _Float16 wh = (_Float16)(wz2*wy2*wx2);
                            const h8 w8 = {wh,wh,wh,wh,wh,wh,wh,wh};
                            const h8* pf = (const h8*)(Fg + ((size_t)((zi2*32+yi2)*32+xi2))*32 + h*16);
                            FVa = __builtin_elementwise_fma(pf[0], w8, FVa);
                            FVb = __builtin_elementwise_fma(pf[1], w8, FVb);
                        }
                    }
                }
            }

            *(h8*)&buf[s*LW + h*16]     = FVa;
            *(h8*)&buf[s*LW + h*16 + 8] = FVb;
        }

        // L1: 32 -> 128, relu. Swapped MFMA: A=weights, B=act -> C[sample=col][ch=quad*4+r]
        {
            h8 act0 = *(const h8*)&buf[sr0*LW + quad*8];
            h8 act1 = *(const h8*)&buf[sr1*LW + quad*8];
            const h8* W = (const h8*)(Wp + OFF_SW0);
            #pragma unroll
            for (int nt=0; nt<8; nt++){
                h8 w = W[nt*64 + lane];
                floatx4 c0v = {0.f,0.f,0.f,0.f}, c1v = {0.f,0.f,0.f,0.f};
                c0v = __builtin_amdgcn_mfma_f32_16x16x32_f16(w, act0, c0v, 0,0,0);
                c1v = __builtin_amdgcn_mfma_f32_16x16x32_f16(w, act1, c1v, 0,0,0);
                *(h4*)&buf[sr0*LW + nt*16 + quad*4] = pack_relu(c0v);
                *(h4*)&buf[sr1*LW + nt*16 + quad*4] = pack_relu(c1v);
            }
        }
        // no barrier: rows are wave-private

        // L2: 128 -> 128, relu
        {
            h8 A0[4], A1[4];
            #pragma unroll
            for (int ks=0;ks<4;ks++){
                A0[ks] = *(const h8*)&buf[sr0*LW + ks*32 + quad*8];
                A1[ks] = *(const h8*)&buf[sr1*LW + ks*32 + quad*8];
            }
            const h8* W = (const h8*)(Wp + OFF_SW1);
            #pragma unroll
            for (int nt=0; nt<8; nt++){
                floatx4 c0v = {0.f,0.f,0.f,0.f}, c1v = {0.f,0.f,0.f,0.f};
                #pragma unroll
                for (int ks=0;ks<4;ks++){
                    h8 w = W[(nt*4+ks)*64 + lane];
                    c0v = __builtin_amdgcn_mfma_f32_16x16x32_f16(w, A0[ks], c0v, 0,0,0);
                    c1v = __builtin_amdgcn_mfma_f32_16x16x32_f16(w, A1[ks], c1v, 0,0,0);
                }
                *(h4*)&buf[sr0*LW + nt*16 + quad*4] = pack_relu(c0v);
                *(h4*)&buf[sr1*LW + nt*16 + quad*4] = pack_relu(c1v);
            }
        }

        // L3: 128 -> 16, no relu. ch=quad*4+r, sample=col. ch0 -> sigmaArr,
        // ch 1..15 -> buf cols 16..30.
        {
            h8 A0[4], A1[4];
            #pragma unroll
            for (int ks=0;ks<4;ks++){
                A0[ks] = *(const h8*)&buf[sr0*LW + ks*32 + quad*8];
                A1[ks] = *(const h8*)&buf[sr1*LW + ks*32 + quad*8];
            }
            const h8* W = (const h8*)(Wp + OFF_SW2);
            floatx4 c0v = {0.f,0.f,0.f,0.f}, c1v = {0.f,0.f,0.f,0.f};
            #pragma unroll
            for (int ks=0;ks<4;ks++){
                h8 w = W[ks*64 + lane];
                c0v = __builtin_amdgcn_mfma_f32_16x16x32_f16(w, A0[ks], c0v, 0,0,0);
                c1v = __builtin_amdgcn_mfma_f32_16x16x32_f16(w, A1[ks], c1v, 0,0,0);
            }
            #pragma unroll
            for (int r=0;r<4;r++){
                int ch = quad*4 + r;
                if (ch == 0){
                    sigmaArr[sr0] = c0v[r];
                    sigmaArr[sr1] = c1v[r];
                } else {
                    buf[sr0*LW + 15 + ch] = (_Float16)c0v[r];
                    buf[sr1*LW + 15 + ch] = (_Float16)c1v[r];
                }
            }
            // SH basis (ray-uniform) -> cols 0..15 of this wave's 32 rows
            const float dn = sqrtf(dx*dx+dy*dy+dz*dz);
            const float X = dx/dn, Y = dy/dn, Z = dz/dn;
            const float X2=X*X, Y2=Y*Y, Z2=Z*Z;
            float sh[16];
            sh[0]= 0.28209479177387814f;
            sh[1]=-0.48860251190291987f*Y;
            sh[2]= 0.48860251190291987f*Z;
            sh[3]=-0.48860251190291987f*X;
            sh[4]= 1.0925484305920792f*X*Y;
            sh[5]=-1.0925484305920792f*Y*Z;
            sh[6]= 0.94617469575756f*Z2 - 0.31539156525252f;
            sh[7]=-1.0925484305920792f*X*Z;
            sh[8]= 0.5462742152960396f*(X2-Y2);
            sh[9]= 0.5900435899266435f*Y*(-3.0f*X2+Y2);
            sh[10]=2.890611442640554f*X*Y*Z;
            sh[11]=0.4570457994644657f*Y*(1.0f-5.0f*Z2);
            sh[12]=0.3731763325901154f*Z*(5.0f*Z2-3.0f);
            sh[13]=0.4570457994644657f*X*(1.0f-5.0f*Z2);
            sh[14]=1.445305721320277f*Z*(X2-Y2);
            sh[15]=0.5900435899266435f*X*(-X2+3.0f*Y2);
            if (lane < 32){
                int row = rowbase + lane;
                #pragma unroll
                for (int k=0;k<16;k++) buf[row*LW + k] = (_Float16)sh[k];
            }
        }

        // CL1: 31(pad32) -> 64, relu
        {
            h8 act0 = *(const h8*)&buf[sr0*LW + quad*8];
            h8 act1 = *(const h8*)&buf[sr1*LW + quad*8];
            const h8* W = (const h8*)(Wp + OFF_CW0);
            #pragma unroll
            for (int nt=0; nt<4; nt++){
                h8 w = W[nt*64 + lane];
                floatx4 c0v = {0.f,0.f,0.f,0.f}, c1v = {0.f,0.f,0.f,0.f};
                c0v = __builtin_amdgcn_mfma_f32_16x16x32_f16(w, act0, c0v, 0,0,0);
                c1v = __builtin_amdgcn_mfma_f32_16x16x32_f16(w, act1, c1v, 0,0,0);
                *(h4*)&buf[sr0*LW + nt*16 + quad*4] = pack_relu(c0v);
                *(h4*)&buf[sr1*LW + nt*16 + quad*4] = pack_relu(c1v);
            }
        }

        // CL2: 64 -> 64, relu
        {
            h8 A0[2], A1[2];
            #pragma unroll
            for (int ks=0;ks<2;ks++){
                A0[ks] = *(const h8*)&buf[sr0*LW + ks*32 + quad*8];
                A1[ks] = *(const h8*)&buf[sr1*LW + ks*32 + quad*8];
            }
            const h8* W = (const h8*)(Wp + OFF_CW1);
            #pragma unroll
            for (int nt=0; nt<4; nt++){
                floatx4 c0v = {0.f,0.f,0.f,0.f}, c1v = {0.f,0.f,0.f,0.f};
                #pragma unroll
                for (int ks=0;ks<2;ks++){
                    h8 w = W[(nt*2+ks)*64 + lane];
                    c0v = __builtin_amdgcn_mfma_f32_16x16x32_f16(w, A0[ks], c0v, 0,0,0);
                    c1v = __builtin_amdgcn_mfma_f32_16x16x32_f16(w, A1[ks], c1v, 0,0,0);
                }
                *(h4*)&buf[sr0*LW + nt*16 + quad*4] = pack_relu(c0v);
                *(h4*)&buf[sr1*LW + nt*16 + quad*4] = pack_relu(c1v);
            }
        }

        // CL3: 64 -> 3, no relu. ch=quad*4+r, sample=col -> rgbArr
        {
            h8 A0[2], A1[2];
            #pragma unroll
            for (int ks=0;ks<2;ks++){
                A0[ks] = *(const h8*)&buf[sr0*LW + ks*32 + quad*8];
                A1[ks] = *(const h8*)&buf[sr1*LW + ks*32 + quad*8];
            }
            const h8* W = (const h8*)(Wp + OFF_CW2);
            floatx4 c0v = {0.f,0.f,0.f,0.f}, c1v = {0.f,0.f,0.f,0.f};
            #pragma unroll
            for (int ks=0;ks<2;ks++){
                h8 w = W[ks*64 + lane];
                c0v = __builtin_amdgcn_mfma_f32_16x16x32_f16(w, A0[ks], c0v, 0,0,0);
                c1v = __builtin_amdgcn_mfma_f32_16x16x32_f16(w, A1[ks], c1v, 0,0,0);
            }
            if (quad == 0){
                #pragma unroll
                for (int r=0;r<3;r++){
                    rgbArr[sr0*3 + r] = c0v[r];
                    rgbArr[sr1*3 + r] = c1v[r];
                }
            }
        }
    }

    __syncthreads();   // cross-wave handoff: sigmaArr/rgbArr -> waves 0,1

    // ---------------- compositing (threads 0..127, sample = tid) ----------------
    {
        float alpha = 0.f, rr = 0.f, rg = 0.f, rb = 0.f;
        if (tid < 128){
            float ts0 = nearv + (float)tid     * 0.0352f;
            float ts1 = nearv + (float)(tid+1) * 0.0352f;
            float tmid = 0.5f*(ts0+ts1);
            float dist = ts1 - ts0;
            float px = ox + tmid*dx, py = oy + tmid*dy, pz = oz + tmid*dz;
            bool mask = (fabsf(px)<=1.3f) && (fabsf(py)<=1.3f) && (fabsf(pz)<=1.3f)
                      && (tmid<=tmax) && (tmax>tmin);
            float sg = mask ? fmaxf(sigmaArr[tid], 0.f) : 0.f;
            alpha = 1.0f - expf(-sg*dist);
            if (mask){
                rr = 1.0f/(1.0f+expf(-rgbArr[tid*3+0]));
                rg = 1.0f/(1.0f+expf(-rgbArr[tid*3+1]));
                rb = 1.0f/(1.0f+expf(-rgbArr[tid*3+2]));
            }
        }
        float p = 1.0f - alpha + 1e-10f;
        #pragma unroll
        for (int off=1; off<64; off<<=1){
            float u = __shfl_up(p, off, 64);
            if (lane >= off) p *= u;
        }
        if (tid < 128 && lane == 63) wtot[wv] = p;
        float excl = __shfl_up(p, 1, 64);
        if (lane == 0) excl = 1.0f;
        __syncthreads();
        if (tid < 128){
            float T = excl;
            if (wv == 1) T *= wtot[0];
            float w = alpha * T;
            float v0 = wred64(w*rr);
            float v1 = wred64(w*rg);
            float v2 = wred64(w*rb);
            float v3 = wred64(w);
            if (lane == 0){
                partial[wv*4+0]=v0; partial[wv*4+1]=v1; partial[wv*4+2]=v2; partial[wv*4+3]=v3;
            }
        }
        __syncthreads();
        if (tid == 0){
            float acc = partial[3] + partial[7];
            float bg  = 1.0f - acc;
            out[ray*3+0] = partial[0] + partial[4] + bg;
            out[ray*3+1] = partial[1] + partial[5] + bg;
            out[ray*3+2] = partial[2] + partial[6] + bg;
        }
    }
}

extern "C" void kernel_launch(void* const* d_in, const int* in_sizes, int n_in,
                              void* d_out, int out_size, void* d_ws, size_t ws_size,
                              hipStream_t stream){
    const float* rays_o = (const float*)d_in[0];
    const float* rays_d = (const float*)d_in[1];
    const float* Gxy    = (const float*)d_in[2];
    const float* Gxz    = (const float*)d_in[3];
    const float* Gyz    = (const float*)d_in[4];
    const float* F_grid = (const float*)d_in[5];
    const float* sW0    = (const float*)d_in[6];
    const float* sW1    = (const float*)d_in[7];
    const float* sW2    = (const float*)d_in[8];
    const float* cW0    = (const float*)d_in[9];
    const float* cW1    = (const float*)d_in[10];
    const float* cW2    = (const float*)d_in[11];

    _Float16* Wp = (_Float16*)d_ws;                     // packed weights (59.4 KB)
    _Float16* Gp = Wp + PACK_TOTAL;                     // padded fp16 triplanes, 7.08 MB
    _Float16* Fg = Gp + (size_t)3*TRI_CELLS*32;         // fp16 F_grid, 2.1 MB

    prep_all<<<PREP_TOTAL/256, 256, 0, stream>>>(sW0,sW1,sW2,cW0,cW1,cW2,
                                                 Gxy,Gxz,Gyz,F_grid, Wp,Gp,Fg);
    nerf_fused<<<2048, 256, 0, stream>>>(rays_o, rays_d, Gp, Fg, Wp, (float*)d_out);
}

// Round 16
// 127.939 us; speedup vs baseline: 1.0847x; 1.0421x over previous
//
#include <hip/hip_runtime.h>
#include <math.h>

#define RES 192
#define RANK 8
#define NI 128
#define LW 136   // padded LDS row width (halfs)

typedef __attribute__((ext_vector_type(8))) _Float16 h8;
typedef __attribute__((ext_vector_type(2))) _Float16 h2f;
typedef __attribute__((ext_vector_type(4))) float floatx4;

// packed-weight offsets in halfs (each fragment chunk: 64 lanes * 8 fp16)
#define OFF_SW0 0        // 8 ntiles * 1 kstep  * 512 = 4096
#define OFF_SW1 4096     // 8 * 4 * 512 = 16384
#define OFF_SW2 20480    // 1 * 4 * 512 = 2048
#define OFF_CW0 22528    // 4 * 1 * 512 = 2048
#define OFF_CW1 24576    // 4 * 2 * 512 = 4096
#define OFF_CW2 28672    // 1 * 2 * 512 = 1024
#define PACK_TOTAL 29696

#define TRI_CELLS (RES*RES)          // 36864 cells per plane
#define TRI_TOTAL (3*TRI_CELLS*24)   // 2654208
#define FG_TOTAL  (32*32*32*32)      // 1048576
#define PREP_TOTAL (PACK_TOTAL + TRI_TOTAL + FG_TOTAL)   // 3732480 = 14580*256

__device__ __forceinline__ void prep_idx(float c, int size, int& i0, float& f){
    float idx = (c + 1.0f)*0.5f*(float)(size-1);
    idx = fminf(fmaxf(idx, 0.0f), (float)(size-1));
    int ii = (int)idx;               // idx >= 0, trunc == floor
    if (ii > size-2) ii = size-2;
    i0 = ii;
    f = idx - (float)ii;
}

__device__ __forceinline__ float wred64(float v){
    #pragma unroll
    for (int o=32;o>0;o>>=1) v += __shfl_down(v, o, 64);
    return v;
}

// pair exchange: xor-1 lane shuffle of an h8 (4 dword moves)
__device__ __forceinline__ h8 shx1(h8 v){
    union { h8 h; int i[4]; } u; u.h = v;
    #pragma unroll
    for (int k=0;k<4;k++) u.i[k] = __shfl_xor(u.i[k], 1, 64);
    return u.h;
}

// ---- fused prep: weight packing + fp16 table conversion ----
__global__ void __launch_bounds__(256) prep_all(
    const float* __restrict__ sW0, const float* __restrict__ sW1,
    const float* __restrict__ sW2, const float* __restrict__ cW0,
    const float* __restrict__ cW1, const float* __restrict__ cW2,
    const float* __restrict__ Gxy, const float* __restrict__ Gxz,
    const float* __restrict__ Gyz, const float* __restrict__ F_grid,
    _Float16* __restrict__ Wp, _Float16* __restrict__ Gp, _Float16* __restrict__ Fg)
{
    int e = blockIdx.x*256 + threadIdx.x;
    if (e < PACK_TOTAL){
        const float* src; int K, N, ksteps, base;
        if      (e < OFF_SW1){ src=sW0; K=32;  N=128; ksteps=1; base=OFF_SW0; }
        else if (e < OFF_SW2){ src=sW1; K=128; N=128; ksteps=4; base=OFF_SW1; }
        else if (e < OFF_CW0){ src=sW2; K=128; N=16;  ksteps=4; base=OFF_SW2; }
        else if (e < OFF_CW1){ src=cW0; K=31;  N=64;  ksteps=1; base=OFF_CW0; }
        else if (e < OFF_CW2){ src=cW1; K=64;  N=64;  ksteps=2; base=OFF_CW1; }
        else                 { src=cW2; K=64;  N=3;   ksteps=2; base=OFF_CW2; }
        int i = e - base;
        int j = i & 7, lane = (i>>3)&63, t = i>>9;
        int ks = t % ksteps, nt = t / ksteps;
        int k = ks*32 + (lane>>4)*8 + j;
        int n = nt*16 + (lane&15);
        float v = (k < K && n < N) ? src[k*N + n] : 0.0f;
        Wp[e] = (_Float16)v;
        return;
    }
    int e2 = e - PACK_TOTAL;
    if (e2 < TRI_TOTAL){
        int p    = e2 / (TRI_CELLS*24);
        int rem  = e2 - p*(TRI_CELLS*24);
        int cell = rem / 24;
        int c    = rem - cell*24;
        const float* src = (p==0) ? Gxy : (p==1) ? Gxz : Gyz;
        Gp[((size_t)(p*TRI_CELLS + cell))*32 + c] = (_Float16)src[(size_t)cell*24 + c];
        return;
    }
    int e3 = e2 - TRI_TOTAL;
    Fg[e3] = (_Float16)F_grid[e3];
}

// --------- fused kernel: gather + MFMA MLPs + compositing (block = ray) ---------
// Wave wv owns samples/rows [32wv,32wv+32) end-to-end: gather (2 lanes/sample,
// triplane YZ rows deduped across pair lanes via shfl) -> own buf rows -> 6 MFMA
// layers, no inter-phase barriers; then cross-wave composite.
__launch_bounds__(256, 4)
__global__ void nerf_fused(
    const float* __restrict__ rays_o, const float* __restrict__ rays_d,
    const _Float16* __restrict__ Gp, const _Float16* __restrict__ Fg,
    const _Float16* __restrict__ Wp, float* __restrict__ out)
{
    __shared__ _Float16 buf[128*LW];     // activations; rows are WAVE-PRIVATE
    __shared__ float sigmaArr[128];
    __shared__ float rgbArr[128*3];
    __shared__ float wtot[2];
    __shared__ float partial[8];

    const int tid  = threadIdx.x;
    const int lane = tid & 63;
    const int wv   = tid >> 6;           // wave 0..3
    const int ray  = blockIdx.x;

    const int rowbase = wv*32;
    const int col  = lane & 15;
    const int quad = lane >> 4;
    const int ar0  = rowbase + col;        // A row, mtile 0
    const int ar1  = ar0 + 16;             // A row, mtile 1

    const float ox = rays_o[ray*3+0], oy = rays_o[ray*3+1], oz = rays_o[ray*3+2];
    const float dx = rays_d[ray*3+0], dy = rays_d[ray*3+1], dz = rays_d[ray*3+2];

    float sdx = (fabsf(dx) < 1e-9f) ? 1e-9f : dx;
    float sdy = (fabsf(dy) < 1e-9f) ? 1e-9f : dy;
    float sdz = (fabsf(dz) < 1e-9f) ? 1e-9f : dz;
    float t1x = (-1.3f - ox)/sdx, t2x = (1.3f - ox)/sdx;
    float t1y = (-1.3f - oy)/sdy, t2y = (1.3f - oy)/sdy;
    float t1z = (-1.3f - oz)/sdz, t2z = (1.3f - oz)/sdz;
    float tmin = fmaxf(fminf(t1x,t2x), fmaxf(fminf(t1y,t2y), fminf(t1z,t2z)));
    float tmax = fminf(fmaxf(t1x,t2x), fminf(fmaxf(t1y,t2y), fmaxf(t1z,t2z)));
    float nearv = fmaxf(tmin, 0.0f);

    // wave-skip: if all 32 samples of this wave are masked, outputs never read
    bool skipAll;
    {
        int sid = rowbase + (lane & 31);
        float w_ts0 = nearv + (float)sid     * 0.0352f;
        float w_ts1 = nearv + (float)(sid+1) * 0.0352f;
        float w_tm  = 0.5f*(w_ts0+w_ts1);
        float wpx = ox + w_tm*dx, wpy = oy + w_tm*dy, wpz = oz + w_tm*dz;
        bool m = (fabsf(wpx)<=1.3f) && (fabsf(wpy)<=1.3f) && (fabsf(wpz)<=1.3f)
               && (w_tm<=tmax) && (tmax>tmin);
        skipAll = (__ballot(m) == 0ULL);
    }

    if (!skipAll){
        // ---- gather: 2 lanes per sample ----
        {
            const int s = rowbase + (lane >> 1);
            const int h = lane & 1;        // zc half / F-grid ch half

            float ts0 = nearv + (float)s     * 0.0352f;
            float ts1 = nearv + (float)(s+1) * 0.0352f;
            float tmid = 0.5f*(ts0+ts1);
            float px = ox + tmid*dx, py = oy + tmid*dy, pz = oz + tmid*dz;
            bool mask = (fabsf(px)<=1.3f) && (fabsf(py)<=1.3f) && (fabsf(pz)<=1.3f)
                      && (tmid<=tmax) && (tmax>tmin);

            h8 FVa = {0,0,0,0,0,0,0,0};
            h8 FVb = {0,0,0,0,0,0,0,0};

            if (mask){
                float p0 = (px/1.3f + 1.0f)*192.0f/2.0f*2.0f/192.0f - 1.0f;
                float p1 = (py/1.3f + 1.0f)*192.0f/2.0f*2.0f/192.0f - 1.0f;
                float p2 = (pz/1.3f + 1.0f)*192.0f/2.0f*2.0f/192.0f - 1.0f;

                int x0, y0, z0; float fx, fy, fz;
                prep_idx(p0, RES, x0, fx);
                prep_idx(p1, RES, y0, fy);
                prep_idx(p2, RES, z0, fz);

                // this lane: zc = h; owns YZ row yc = h, partner row via shfl
                const int zi  = z0 + h;
                const float wzc = h ? fz : (1.0f - fz);
                const int yiA = y0 + h;        // yc = h    (yo=0)
                const int yiB = y0 + 1 - h;    // yc = 1-h  (yo=1)

                h8 XYA[3], XYB[3], XZ0[3], XZ1[3], YZo0[3], YZo1[3];
                {
                    const h8* pxyA = (const h8*)(Gp + ((size_t)(zi*RES + yiA))*32);
                    const h8* pxyB = (const h8*)(Gp + ((size_t)(zi*RES + yiB))*32);
                    const h8* px0  = (const h8*)(Gp + ((size_t)(TRI_CELLS + zi*RES + x0  ))*32);
                    const h8* px1  = (const h8*)(Gp + ((size_t)(TRI_CELLS + zi*RES + x0+1))*32);
                    const h8* py0  = (const h8*)(Gp + ((size_t)(2*TRI_CELLS + yiA*RES + x0  ))*32);
                    const h8* py1  = (const h8*)(Gp + ((size_t)(2*TRI_CELLS + yiA*RES + x0+1))*32);
                    #pragma unroll
                    for (int q=0;q<3;q++){
                        XYA[q]=pxyA[q]; XYB[q]=pxyB[q];
                        XZ0[q]=px0[q];  XZ1[q]=px1[q];
                        YZo0[q]=py0[q]; YZo1[q]=py1[q];
                    }
                }
                // partner's YZ row (yc = 1-h); pair lanes have identical mask
                h8 YZp0[3], YZp1[3];
                #pragma unroll
                for (int q=0;q<3;q++){ YZp0[q]=shx1(YZo0[q]); YZp1[q]=shx1(YZo1[q]); }

                const float wyA = h ? fy : (1.0f - fy);   // weight for yc=h
                const float wyB = h ? (1.0f - fy) : fy;   // weight for yc=1-h

                h8 ACC0 = {0,0,0,0,0,0,0,0};
                h8 ACC1 = {0,0,0,0,0,0,0,0};
                h8 ACC2 = {0,0,0,0,0,0,0,0};
                #pragma unroll
                for (int yo=0; yo<2; yo++){
                    const float wy = yo ? wyB : wyA;
                    #pragma unroll
                    for (int xc=0; xc<2; xc++){
                        const float wx = xc ? fx : (1.0f - fx);
                        const _Float16 wh = (_Float16)(wzc*wy*wx);
                        const h8 w8 = {wh,wh,wh,wh,wh,wh,wh,wh};
                        h8 Q0, Q1, Q2;
                        if (yo==0){
                            const h8* YZv = xc ? YZo1 : YZo0;
                            Q0 = (XYA[0]*(xc?XZ1[0]:XZ0[0]))*YZv[0];
                            Q1 = (XYA[1]*(xc?XZ1[1]:XZ0[1]))*YZv[1];
                            Q2 = (XYA[2]*(xc?XZ1[2]:XZ0[2]))*YZv[2];
                        } else {
                            const h8* YZv = xc ? YZp1 : YZp0;
                            Q0 = (XYB[0]*(xc?XZ1[0]:XZ0[0]))*YZv[0];
                            Q1 = (XYB[1]*(xc?XZ1[1]:XZ0[1]))*YZv[1];
                            Q2 = (XYB[2]*(xc?XZ1[2]:XZ0[2]))*YZv[2];
                        }
                        ACC0 = __builtin_elementwise_fma(Q0, w8, ACC0);
                        ACC1 = __builtin_elementwise_fma(Q1, w8, ACC1);
                        ACC2 = __builtin_elementwise_fma(Q2, w8, ACC2);
                    }
                }
                // horizontal sums 8 -> 1
                h2f a0h = __builtin_shufflevector(ACC0,ACC0,0,1) + __builtin_shufflevector(ACC0,ACC0,2,3);
                h2f b0h = __builtin_shufflevector(ACC0,ACC0,4,5) + __builtin_shufflevector(ACC0,ACC0,6,7);
                h2f c0h = a0h + b0h;
                float gv0 = (float)c0h[0] + (float)c0h[1];
                h2f a1h = __builtin_shufflevector(ACC1,ACC1,0,1) + __builtin_shufflevector(ACC1,ACC1,2,3);
                h2f b1h = __builtin_shufflevector(ACC1,ACC1,4,5) + __builtin_shufflevector(ACC1,ACC1,6,7);
                h2f c1h = a1h + b1h;
                float gv1 = (float)c1h[0] + (float)c1h[1];
                h2f a2h = __builtin_shufflevector(ACC2,ACC2,0,1) + __builtin_shufflevector(ACC2,ACC2,2,3);
                h2f b2h = __builtin_shufflevector(ACC2,ACC2,4,5) + __builtin_shufflevector(ACC2,ACC2,6,7);
                h2f c2h = a2h + b2h;
                float gv2 = (float)c2h[0] + (float)c2h[1];

                // combine the two zc halves
                gv0 += __shfl_xor(gv0, 1, 64);
                gv1 += __shfl_xor(gv1, 1, 64);
                gv2 += __shfl_xor(gv2, 1, 64);

                // F-grid: channels [16h,16h+16) of all 8 corners
                int a0,b0,c0; float fa,fb,fc;
                prep_idx(gv2, 32, a0, fa);
                prep_idx(gv1, 32, b0, fb);
                prep_idx(gv0, 32, c0, fc);
                #pragma unroll
                for (int zc=0; zc<2; zc++){
                    const int zi2 = a0+zc; const float wz2 = zc ? fa : 1.f-fa;
                    #pragma unroll
                    for (int yc=0; yc<2; yc++){
                        const int yi2 = b0+yc; const float wy2 = yc ? fb : 1.f-fb;
                        #pragma unroll
                        for (int xc=0; xc<2; xc++){
                            const int xi2 = c0+xc; const float wx2 = xc ? fc : 1.f-fc;
                            const _Float16 wh = (_Float16)(wz2*wy2*wx2);
                            const h8 w8 = {wh,wh,wh,wh,wh,wh,wh,wh};
                            const h8* pf = (const h8*)(Fg + ((size_t)((zi2*32+yi2)*32+xi2))*32 + h*16);
                            FVa = __builtin_elementwise_fma(pf[0], w8, FVa);
                            FVb = __builtin_elementwise_fma(pf[1], w8, FVb);
                        }
                    }
                }
            }

            *(h8*)&buf[s*LW + h*16]     = FVa;
            *(h8*)&buf[s*LW + h*16 + 8] = FVb;
        }

        // L1: 32 -> 128, relu (in-place safe: a0/a1 register-resident first)
        {
            h8 a0 = *(const h8*)&buf[ar0*LW + quad*8];
            h8 a1 = *(const h8*)&buf[ar1*LW + quad*8];
            const h8* W = (const h8*)(Wp + OFF_SW0);
            #pragma unroll
            for (int nt=0; nt<8; nt++){
                h8 b = W[nt*64 + lane];
                floatx4 c0v = {0.f,0.f,0.f,0.f}, c1v = {0.f,0.f,0.f,0.f};
                c0v = __builtin_amdgcn_mfma_f32_16x16x32_f16(a0, b, c0v, 0,0,0);
                c1v = __builtin_amdgcn_mfma_f32_16x16x32_f16(a1, b, c1v, 0,0,0);
                #pragma unroll
                for (int r=0;r<4;r++){
                    int row0 = rowbase + quad*4 + r;
                    buf[row0*LW      + nt*16 + col] = (_Float16)fmaxf(c0v[r],0.f);
                    buf[(row0+16)*LW + nt*16 + col] = (_Float16)fmaxf(c1v[r],0.f);
                }
            }
        }

        // L2: 128 -> 128, relu
        {
            h8 A0[4], A1[4];
            #pragma unroll
            for (int ks=0;ks<4;ks++){
                A0[ks] = *(const h8*)&buf[ar0*LW + ks*32 + quad*8];
                A1[ks] = *(const h8*)&buf[ar1*LW + ks*32 + quad*8];
            }
            const h8* W = (const h8*)(Wp + OFF_SW1);
            #pragma unroll
            for (int nt=0; nt<8; nt++){
                floatx4 c0v = {0.f,0.f,0.f,0.f}, c1v = {0.f,0.f,0.f,0.f};
                #pragma unroll
                for (int ks=0;ks<4;ks++){
                    h8 b = W[(nt*4+ks)*64 + lane];
                    c0v = __builtin_amdgcn_mfma_f32_16x16x32_f16(A0[ks], b, c0v, 0,0,0);
                    c1v = __builtin_amdgcn_mfma_f32_16x16x32_f16(A1[ks], b, c1v, 0,0,0);
                }
                #pragma unroll
                for (int r=0;r<4;r++){
                    int row0 = rowbase + quad*4 + r;
                    buf[row0*LW      + nt*16 + col] = (_Float16)fmaxf(c0v[r],0.f);
                    buf[(row0+16)*LW + nt*16 + col] = (_Float16)fmaxf(c1v[r],0.f);
                }
            }
        }

        // L3: 128 -> 16 (no relu); col0 -> sigmaArr, cols 1..15 -> buf 16..30
        {
            h8 A0[4], A1[4];
            #pragma unroll
            for (int ks=0;ks<4;ks++){
                A0[ks] = *(const h8*)&buf[ar0*LW + ks*32 + quad*8];
                A1[ks] = *(const h8*)&buf[ar1*LW + ks*32 + quad*8];
            }
            const h8* W = (const h8*)(Wp + OFF_SW2);
            floatx4 c0v = {0.f,0.f,0.f,0.f}, c1v = {0.f,0.f,0.f,0.f};
            #pragma unroll
            for (int ks=0;ks<4;ks++){
                h8 b = W[ks*64 + lane];
                c0v = __builtin_amdgcn_mfma_f32_16x16x32_f16(A0[ks], b, c0v, 0,0,0);
                c1v = __builtin_amdgcn_mfma_f32_16x16x32_f16(A1[ks], b, c1v, 0,0,0);
            }
            #pragma unroll
            for (int r=0;r<4;r++){
                int row0 = rowbase + quad*4 + r;
                if (col == 0){
                    sigmaArr[row0]    = c0v[r];
                    sigmaArr[row0+16] = c1v[r];
                } else {
                    buf[row0*LW      + 15 + col] = (_Float16)c0v[r];
                    buf[(row0+16)*LW + 15 + col] = (_Float16)c1v[r];
                }
            }
            // SH basis (ray-uniform) -> cols 0..15
            const float dn = sqrtf(dx*dx+dy*dy+dz*dz);
            const float X = dx/dn, Y = dy/dn, Z = dz/dn;
            const float X2=X*X, Y2=Y*Y, Z2=Z*Z;
            float sh[16];
            sh[0]= 0.28209479177387814f;
            sh[1]=-0.48860251190291987f*Y;
            sh[2]= 0.48860251190291987f*Z;
            sh[3]=-0.48860251190291987f*X;
            sh[4]= 1.0925484305920792f*X*Y;
            sh[5]=-1.0925484305920792f*Y*Z;
            sh[6]= 0.94617469575756f*Z2 - 0.31539156525252f;
            sh[7]=-1.0925484305920792f*X*Z;
            sh[8]= 0.5462742152960396f*(X2-Y2);
            sh[9]= 0.5900435899266435f*Y*(-3.0f*X2+Y2);
            sh[10]=2.890611442640554f*X*Y*Z;
            sh[11]=0.4570457994644657f*Y*(1.0f-5.0f*Z2);
            sh[12]=0.3731763325901154f*Z*(5.0f*Z2-3.0f);
            sh[13]=0.4570457994644657f*X*(1.0f-5.0f*Z2);
            sh[14]=1.445305721320277f*Z*(X2-Y2);
            sh[15]=0.5900435899266435f*X*(-X2+3.0f*Y2);
            if (lane < 32){
                int row = rowbase + lane;
                #pragma unroll
                for (int k=0;k<16;k++) buf[row*LW + k] = (_Float16)sh[k];
            }
        }

        // CL1: 31(pad32) -> 64, relu
        {
            h8 a0 = *(const h8*)&buf[ar0*LW + quad*8];
            h8 a1 = *(const h8*)&buf[ar1*LW + quad*8];
            const h8* W = (const h8*)(Wp + OFF_CW0);
            #pragma unroll
            for (int nt=0; nt<4; nt++){
                h8 b = W[nt*64 + lane];
                floatx4 c0v = {0.f,0.f,0.f,0.f}, c1v = {0.f,0.f,0.f,0.f};
                c0v = __builtin_amdgcn_mfma_f32_16x16x32_f16(a0, b, c0v, 0,0,0);
                c1v = __builtin_amdgcn_mfma_f32_16x16x32_f16(a1, b, c1v, 0,0,0);
                #pragma unroll
                for (int r=0;r<4;r++){
                    int row0 = rowbase + quad*4 + r;
                    buf[row0*LW      + nt*16 + col] = (_Float16)fmaxf(c0v[r],0.f);
                    buf[(row0+16)*LW + nt*16 + col] = (_Float16)fmaxf(c1v[r],0.f);
                }
            }
        }

        // CL2: 64 -> 64, relu
        {
            h8 A0[2], A1[2];
            #pragma unroll
            for (int ks=0;ks<2;ks++){
                A0[ks] = *(const h8*)&buf[ar0*LW + ks*32 + quad*8];
                A1[ks] = *(const h8*)&buf[ar1*LW + ks*32 + quad*8];
            }
            const h8* W = (const h8*)(Wp + OFF_CW1);
            #pragma unroll
            for (int nt=0; nt<4; nt++){
                floatx4 c0v = {0.f,0.f,0.f,0.f}, c1v = {0.f,0.f,0.f,0.f};
                #pragma unroll
                for (int ks=0;ks<2;ks++){
                    h8 b = W[(nt*2+ks)*64 + lane];
                    c0v = __builtin_amdgcn_mfma_f32_16x16x32_f16(A0[ks], b, c0v, 0,0,0);
                    c1v = __builtin_amdgcn_mfma_f32_16x16x32_f16(A1[ks], b, c1v, 0,0,0);
                }
                #pragma unroll
                for (int r=0;r<4;r++){
                    int row0 = rowbase + quad*4 + r;
                    buf[row0*LW      + nt*16 + col] = (_Float16)fmaxf(c0v[r],0.f);
                    buf[(row0+16)*LW + nt*16 + col] = (_Float16)fmaxf(c1v[r],0.f);
                }
            }
        }

        // CL3: 64 -> 3, no relu -> rgbArr
        {
            h8 A0[2], A1[2];
            #pragma unroll
            for (int ks=0;ks<2;ks++){
                A0[ks] = *(const h8*)&buf[ar0*LW + ks*32 + quad*8];
                A1[ks] = *(const h8*)&buf[ar1*LW + ks*32 + quad*8];
            }
            const h8* W = (const h8*)(Wp + OFF_CW2);
            floatx4 c0v = {0.f,0.f,0.f,0.f}, c1v = {0.f,0.f,0.f,0.f};
            #pragma unroll
            for (int ks=0;ks<2;ks++){
                h8 b = W[ks*64 + lane];
                c0v = __builtin_amdgcn_mfma_f32_16x16x32_f16(A0[ks], b, c0v, 0,0,0);
                c1v = __builtin_amdgcn_mfma_f32_16x16x32_f16(A1[ks], b, c1v, 0,0,0);
            }
            if (col < 3){
                #pragma unroll
                for (int r=0;r<4;r++){
                    int row0 = rowbase + quad*4 + r;
                    rgbArr[row0*3 + col]      = c0v[r];
                    rgbArr[(row0+16)*3 + col] = c1v[r];
                }
            }
        }
    }

    __syncthreads();   // cross-wave handoff: sigmaArr/rgbArr -> waves 0,1

    // ---------------- compositing (threads 0..127, sample = tid) ----------------
    {
        float alpha = 0.f, rr = 0.f, rg = 0.f, rb = 0.f;
        if (tid < 128){
            float ts0 = nearv + (float)tid     * 0.0352f;
            float ts1 = nearv + (float)(tid+1) * 0.0352f;
            float tmid = 0.5f*(ts0+ts1);
            float dist = ts1 - ts0;
            float px = ox + tmid*dx, py = oy + tmid*dy, pz = oz + tmid*dz;
            bool mask = (fabsf(px)<=1.3f) && (fabsf(py)<=1.3f) && (fabsf(pz)<=1.3f)
                      && (tmid<=tmax) && (tmax>tmin);
            float sg = mask ? fmaxf(sigmaArr[tid], 0.f) : 0.f;
            alpha = 1.0f - expf(-sg*dist);
            if (mask){
                rr = 1.0f/(1.0f+expf(-rgbArr[tid*3+0]));
                rg = 1.0f/(1.0f+expf(-rgbArr[tid*3+1]));
                rb = 1.0f/(1.0f+expf(-rgbArr[tid*3+2]));
            }
        }
        float p = 1.0f - alpha + 1e-10f;
        #pragma unroll
        for (int off=1; off<64; off<<=1){
            float u = __shfl_up(p, off, 64);
            if (lane >= off) p *= u;
        }
        if (tid < 128 && lane == 63) wtot[wv] = p;
        float excl = __shfl_up(p, 1, 64);
        if (lane == 0) excl = 1.0f;
        __syncthreads();
        if (tid < 128){
            float T = excl;
            if (wv == 1) T *= wtot[0];
            float w = alpha * T;
            float v0 = wred64(w*rr);
            float v1 = wred64(w*rg);
            float v2 = wred64(w*rb);
            float v3 = wred64(w);
            if (lane == 0){
                partial[wv*4+0]=v0; partial[wv*4+1]=v1; partial[wv*4+2]=v2; partial[wv*4+3]=v3;
            }
        }
        __syncthreads();
        if (tid == 0){
            float acc = partial[3] + partial[7];
            float bg  = 1.0f - acc;
            out[ray*3+0] = partial[0] + partial[4] + bg;
            out[ray*3+1] = partial[1] + partial[5] + bg;
            out[ray*3+2] = partial[2] + partial[6] + bg;
        }
    }
}

extern "C" void kernel_launch(void* const* d_in, const int* in_sizes, int n_in,
                              void* d_out, int out_size, void* d_ws, size_t ws_size,
                              hipStream_t stream){
    const float* rays_o = (const float*)d_in[0];
    const float* rays_d = (const float*)d_in[1];
    const float* Gxy    = (const float*)d_in[2];
    const float* Gxz    = (const float*)d_in[3];
    const float* Gyz    = (const float*)d_in[4];
    const float* F_grid = (const float*)d_in[5];
    const float* sW0    = (const float*)d_in[6];
    const float* sW1    = (const float*)d_in[7];
    const float* sW2    = (const float*)d_in[8];
    const float* cW0    = (const float*)d_in[9];
    const float* cW1    = (const float*)d_in[10];
    const float* cW2    = (const float*)d_in[11];

    _Float16* Wp = (_Float16*)d_ws;                     // packed weights (59.4 KB)
    _Float16* Gp = Wp + PACK_TOTAL;                     // padded fp16 triplanes, 7.08 MB
    _Float16* Fg = Gp + (size_t)3*TRI_CELLS*32;         // fp16 F_grid, 2.1 MB

    prep_all<<<PREP_TOTAL/256, 256, 0, stream>>>(sW0,sW1,sW2,cW0,cW1,cW2,
                                                 Gxy,Gxz,Gyz,F_grid, Wp,Gp,Fg);
    nerf_fused<<<2048, 256, 0, stream>>>(rays_o, rays_d, Gp, Fg, Wp, (float*)d_out);
}